// Round 1
// baseline (831.729 us; speedup 1.0000x reference)
//
#include <hip/hip_runtime.h>
#include <stdint.h>

#define HW 262144          // 512*512
#define LDIM 33

typedef __bf16 bf16x8 __attribute__((ext_vector_type(8)));
typedef float  f32x4  __attribute__((ext_vector_type(4)));

union BF8 { bf16x8 v; unsigned u[4]; };

__device__ __forceinline__ unsigned bfr1(float a) {
  unsigned u = __float_as_uint(a);
  return (u + 0x7fffu + ((u >> 16) & 1u)) >> 16;   // RNE f32->bf16
}
__device__ __forceinline__ unsigned pk2(float a, float b) {
  return bfr1(a) | (bfr1(b) << 16);
}
__device__ __forceinline__ float tanh_fast(float x) {
  return 1.0f - 2.0f / (__expf(2.0f * x) + 1.0f);
}
__device__ __forceinline__ float gelu_t(float x) {
  float t = tanh_fast(0.7978845608028654f * (x + 0.044715f * x * x * x));
  return 0.5f * x * (1.0f + t);
}

// LDS map (65536 B total):
//   [0,     32768)  W1 bf16: 128 rows x 256B, 16B group kg stored at (kg ^ (row&15))
//   [32768, 49152)  W2 bf16:  64 rows x 256B, same swizzle
//   [49152, 65536)  per-wave h: 4 waves x 4096B (32 rows x 128B, group swizz kg^(row&7))
//                   offsets alias the h region (h dead by then), 12B/px.
__global__ __launch_bounds__(256, 2) void local3dlut_kernel(
    const float* __restrict__ img,  const float* __restrict__ ctx,
    const float* __restrict__ lut,  const float* __restrict__ W1,
    const float* __restrict__ b1,   const float* __restrict__ W2,
    const float* __restrict__ b2,   const float* __restrict__ W3,
    const float* __restrict__ b3,   const float* __restrict__ oscp,
    float* __restrict__ out)
{
  __shared__ uint4 smem4[4096];
  char* sm = (char*)smem4;
  const int t    = threadIdx.x;
  const int lane = t & 63;
  const int wv   = t >> 6;        // wave 0..3
  const int n    = lane & 15;
  const int q    = lane >> 4;     // quad 0..3

  // ---- stage W1 (128x128) and W2 (64x128) to LDS as swizzled bf16 ----
  #pragma unroll
  for (int rep = 0; rep < 16; ++rep) {
    int f4 = t + 256 * rep;                 // float4 index 0..4095
    float4 v = ((const float4*)W1)[f4];
    int fi = f4 << 2;
    int o = fi >> 7, k = fi & 127;
    char* dst = sm + o * 256 + (((k >> 3) ^ (o & 15)) << 4) + ((k & 7) << 1);
    *(uint2*)dst = make_uint2(pk2(v.x, v.y), pk2(v.z, v.w));
  }
  #pragma unroll
  for (int rep = 0; rep < 8; ++rep) {
    int f4 = t + 256 * rep;                 // 0..2047
    float4 v = ((const float4*)W2)[f4];
    int fi = f4 << 2;
    int o = fi >> 7, k = fi & 127;
    char* dst = sm + 32768 + o * 256 + (((k >> 3) ^ (o & 15)) << 4) + ((k & 7) << 1);
    *(uint2*)dst = make_uint2(pk2(v.x, v.y), pk2(v.z, v.w));
  }
  __syncthreads();

  // per-lane constants
  float b1r[8], b2r[4], w3r[3][4];
  #pragma unroll
  for (int i = 0; i < 8; ++i) b1r[i] = b1[i * 16 + n];
  #pragma unroll
  for (int i = 0; i < 4; ++i) b2r[i] = b2[i * 16 + n];
  #pragma unroll
  for (int j = 0; j < 3; ++j)
    #pragma unroll
    for (int i = 0; i < 4; ++i) w3r[j][i] = W3[j * 64 + i * 16 + n];
  const float b3r0 = b3[0], b3r1 = b3[1], b3r2 = b3[2];
  const float osc  = oscp[0];

  const int p0   = blockIdx.x * 512;        // 512 px per block, never crosses batch b
  const int bi   = p0 >> 18;
  const int sblk = p0 & (HW - 1);
  const float* ctxB = ctx + (size_t)bi * ((size_t)128 * HW);
  const float* imgB = img + (size_t)bi * ((size_t)3 * HW);
  float*       outB = out + (size_t)bi * ((size_t)3 * HW);
  char* hb = sm + 49152 + wv * 4096;

  #pragma unroll 1
  for (int it = 0; it < 4; ++it) {
    const int sw = sblk + it * 128 + wv * 32;   // wave's 32-px base in image

    // ---- A1 fragments: ctx, 2 mtiles x 4 ksteps (global, fragment order) ----
    BF8 a1[2][4];
    #pragma unroll
    for (int mt = 0; mt < 2; ++mt) {
      const int sA = sw + mt * 16 + n;
      #pragma unroll
      for (int ks = 0; ks < 4; ++ks) {
        const float* cb = ctxB + (size_t)(ks * 32 + q * 8) * HW + sA;
        float v0 = cb[0];
        float v1 = cb[(size_t)1 * HW];
        float v2 = cb[(size_t)2 * HW];
        float v3 = cb[(size_t)3 * HW];
        float v4 = cb[(size_t)4 * HW];
        float v5 = cb[(size_t)5 * HW];
        float v6 = cb[(size_t)6 * HW];
        float v7 = cb[(size_t)7 * HW];
        a1[mt][ks].u[0] = pk2(v0, v1);
        a1[mt][ks].u[1] = pk2(v2, v3);
        a1[mt][ks].u[2] = pk2(v4, v5);
        a1[mt][ks].u[3] = pk2(v6, v7);
      }
    }

    f32x4 acc2[2][4];
    #pragma unroll
    for (int mt = 0; mt < 2; ++mt)
      #pragma unroll
      for (int j = 0; j < 4; ++j) { f32x4 z = {0.f,0.f,0.f,0.f}; acc2[mt][j] = z; }

    #pragma unroll
    for (int half = 0; half < 2; ++half) {
      // ---- GEMM1 over 4 ntiles of this half ----
      f32x4 acc1[2][4];
      #pragma unroll
      for (int mt = 0; mt < 2; ++mt)
        #pragma unroll
        for (int j = 0; j < 4; ++j) { f32x4 z = {0.f,0.f,0.f,0.f}; acc1[mt][j] = z; }

      #pragma unroll
      for (int ks = 0; ks < 4; ++ks) {
        #pragma unroll
        for (int nt4 = 0; nt4 < 4; ++nt4) {
          int row = (half * 4 + nt4) * 16 + n;
          bf16x8 bw = *(const bf16x8*)(sm + row * 256 + ((((ks << 2) + q) ^ n) << 4));
          acc1[0][nt4] = __builtin_amdgcn_mfma_f32_16x16x32_bf16(a1[0][ks].v, bw, acc1[0][nt4], 0, 0, 0);
          acc1[1][nt4] = __builtin_amdgcn_mfma_f32_16x16x32_bf16(a1[1][ks].v, bw, acc1[1][nt4], 0, 0, 0);
        }
      }
      // ---- h1 half: bias + gelu -> bf16 -> LDS (C/D -> A layout transpose) ----
      #pragma unroll
      for (int mt = 0; mt < 2; ++mt)
        #pragma unroll
        for (int nt4 = 0; nt4 < 4; ++nt4) {
          int fl = nt4 * 16 + n;        // feature within half, 0..63
          int kgf = fl >> 3;
          #pragma unroll
          for (int r = 0; r < 4; ++r) {
            int px = mt * 16 + (q << 2) + r;
            float hv = gelu_t(acc1[mt][nt4][r] + b1r[half * 4 + nt4]);
            *(unsigned short*)(hb + px * 128 + ((kgf ^ (px & 7)) << 4) + ((fl & 7) << 1)) =
                (unsigned short)bfr1(hv);
          }
        }
      // ---- GEMM2 partial over this half's 64 features ----
      #pragma unroll
      for (int ks2 = 0; ks2 < 2; ++ks2) {
        bf16x8 a2[2];
        #pragma unroll
        for (int mt = 0; mt < 2; ++mt) {
          int px = mt * 16 + n;
          a2[mt] = *(const bf16x8*)(hb + px * 128 + ((((ks2 << 2) + q) ^ (px & 7)) << 4));
        }
        #pragma unroll
        for (int nt2 = 0; nt2 < 4; ++nt2) {
          int row = nt2 * 16 + n;
          int kg2 = half * 8 + (ks2 << 2) + q;
          bf16x8 bw = *(const bf16x8*)(sm + 32768 + row * 256 + ((kg2 ^ n) << 4));
          acc2[0][nt2] = __builtin_amdgcn_mfma_f32_16x16x32_bf16(a2[0], bw, acc2[0][nt2], 0, 0, 0);
          acc2[1][nt2] = __builtin_amdgcn_mfma_f32_16x16x32_bf16(a2[1], bw, acc2[1][nt2], 0, 0, 0);
        }
      }
    }

    // ---- h2 = gelu(acc2 + b2) in-place; layer3 dot + 16-lane reduce; offsets -> LDS ----
    #pragma unroll
    for (int mt = 0; mt < 2; ++mt)
      #pragma unroll
      for (int nt2 = 0; nt2 < 4; ++nt2)
        #pragma unroll
        for (int r = 0; r < 4; ++r)
          acc2[mt][nt2][r] = gelu_t(acc2[mt][nt2][r] + b2r[nt2]);

    #pragma unroll
    for (int mt = 0; mt < 2; ++mt)
      #pragma unroll
      for (int r = 0; r < 4; ++r) {
        float h0 = acc2[mt][0][r], h1v = acc2[mt][1][r], h2v = acc2[mt][2][r], h3v = acc2[mt][3][r];
        float pa = w3r[0][0]*h0 + w3r[0][1]*h1v + w3r[0][2]*h2v + w3r[0][3]*h3v;
        float pb = w3r[1][0]*h0 + w3r[1][1]*h1v + w3r[1][2]*h2v + w3r[1][3]*h3v;
        float pc = w3r[2][0]*h0 + w3r[2][1]*h1v + w3r[2][2]*h2v + w3r[2][3]*h3v;
        pa += __shfl_xor(pa, 1, 16); pa += __shfl_xor(pa, 2, 16);
        pa += __shfl_xor(pa, 4, 16); pa += __shfl_xor(pa, 8, 16);
        pb += __shfl_xor(pb, 1, 16); pb += __shfl_xor(pb, 2, 16);
        pb += __shfl_xor(pb, 4, 16); pb += __shfl_xor(pb, 8, 16);
        pc += __shfl_xor(pc, 1, 16); pc += __shfl_xor(pc, 2, 16);
        pc += __shfl_xor(pc, 4, 16); pc += __shfl_xor(pc, 8, 16);
        int px = mt * 16 + (q << 2) + r;
        float sel  = (n == 0) ? pa   : ((n == 1) ? pb   : pc);
        float bsel = (n == 0) ? b3r0 : ((n == 1) ? b3r1 : b3r2);
        float ov = tanh_fast(sel + bsel) * osc;
        if (n < 3) *(float*)(hb + px * 12 + (n << 2)) = ov;   // h region dead here
      }

    // ---- final phase: LUT sample + store, lanes 0..31, one px each ----
    if (lane < 32) {
      const int sp = sw + lane;
      float o0 = *(const float*)(hb + lane * 12 + 0);
      float o1 = *(const float*)(hb + lane * 12 + 4);
      float o2 = *(const float*)(hb + lane * 12 + 8);

      float rr = imgB[sp], gg = imgB[HW + sp], bb = imgB[2 * HW + sp];
      float gx = fminf(fmaxf((rr + 1.f) * 0.5f, 0.f), 1.f) * 32.f;  // R -> x (b axis)
      float gy = fminf(fmaxf((gg + 1.f) * 0.5f, 0.f), 1.f) * 32.f;  // G -> y (g axis)
      float gz = fminf(fmaxf((bb + 1.f) * 0.5f, 0.f), 1.f) * 32.f;  // B -> z (r axis)
      int x0 = (int)gx, y0 = (int)gy, z0 = (int)gz;
      float fx = gx - (float)x0, fy = gy - (float)y0, fz = gz - (float)z0;
      int x1 = min(x0 + 1, 32), y1 = min(y0 + 1, 32), z1 = min(z0 + 1, 32);
      int zy00 = (z0 * LDIM + y0) * LDIM, zy01 = (z0 * LDIM + y1) * LDIM;
      int zy10 = (z1 * LDIM + y0) * LDIM, zy11 = (z1 * LDIM + y1) * LDIM;
      int i000 = (zy00 + x0) * 3, i001 = (zy00 + x1) * 3;
      int i010 = (zy01 + x0) * 3, i011 = (zy01 + x1) * 3;
      int i100 = (zy10 + x0) * 3, i101 = (zy10 + x1) * 3;
      int i110 = (zy11 + x0) * 3, i111 = (zy11 + x1) * 3;
      const float* L = lut;
      float so[3];
      #pragma unroll
      for (int ch = 0; ch < 3; ++ch) {
        float c000 = L[i000 + ch], c001 = L[i001 + ch];
        float c010 = L[i010 + ch], c011 = L[i011 + ch];
        float c100 = L[i100 + ch], c101 = L[i101 + ch];
        float c110 = L[i110 + ch], c111 = L[i111 + ch];
        float c00 = c000 + fx * (c001 - c000);
        float c01 = c010 + fx * (c011 - c010);
        float c10 = c100 + fx * (c101 - c100);
        float c11 = c110 + fx * (c111 - c110);
        float ca  = c00 + fy * (c01 - c00);
        float cb2 = c10 + fy * (c11 - c10);
        so[ch] = ca + fz * (cb2 - ca);
      }
      outB[sp]          = so[0] * 2.f - 1.f + o0;
      outB[HW + sp]     = so[1] * 2.f - 1.f + o1;
      outB[2 * HW + sp] = so[2] * 2.f - 1.f + o2;
    }
  }
}

extern "C" void kernel_launch(void* const* d_in, const int* in_sizes, int n_in,
                              void* d_out, int out_size, void* d_ws, size_t ws_size,
                              hipStream_t stream) {
  const float* img = (const float*)d_in[0];
  const float* ctx = (const float*)d_in[1];
  const float* lut = (const float*)d_in[2];
  const float* W1  = (const float*)d_in[3];
  const float* b1  = (const float*)d_in[4];
  const float* W2  = (const float*)d_in[5];
  const float* b2  = (const float*)d_in[6];
  const float* W3  = (const float*)d_in[7];
  const float* b3  = (const float*)d_in[8];
  const float* osc = (const float*)d_in[9];
  float* out = (float*)d_out;
  // 2048 blocks x 512 px = 1,048,576 px; 256 threads (4 waves), 64 KB LDS, 2 blocks/CU
  local3dlut_kernel<<<dim3(2048), dim3(256), 0, stream>>>(
      img, ctx, lut, W1, b1, W2, b2, W3, b3, osc, out);
}